// Round 1
// baseline (65.346 us; speedup 1.0000x reference)
//
#include <hip/hip_runtime.h>

// Problem constants (from reference):
//   x: (8, 3, 64, 64) f32, W: (64, 3, 5, 5) f32, K=5, STRIDE=1, PAD=2
//   out[n,f,y,x] = sum_{c,kh,kw} W[f,c,kh,kw]*xp[n,c,y+kh,x+kw]
//                  - 0.5*(||patch||^2 + ||W_f||^2)
//   out: (8, 64, 64, 64) f32

#define CH   3
#define NF   64
#define KK   5
#define PADC 2
#define HH   64
#define WW   64

#define NROWS (CH * KK)     // 15 padded input rows needed per output row
#define ROWW  68            // 64 + 2*PAD
#define WSTRIDE 124         // per-filter LDS stride (floats); 124%32=28 -> 2-way max
                            // within filter: (c*5+kh)*8 + kw  (kw padded to 8)

__global__ __launch_bounds__(256) void euclid_conv_kernel(
    const float* __restrict__ x,
    const float* __restrict__ Wt,
    float* __restrict__ out)
{
    __shared__ float xs[NROWS * ROWW];      // 15*68 = 1020 floats
    __shared__ float ws[NF * WSTRIDE];      // 64*124 = 7936 floats
    __shared__ float w2s[NF];

    const int t   = threadIdx.x;
    const int blk = blockIdx.x;             // 0..511
    const int n   = blk >> 6;
    const int y   = blk & 63;

    // ---- stage padded input rows: xs[(c*5+kh)*68 + col] = xp[n,c,y+kh,col] ----
    for (int idx = t; idx < NROWS * ROWW; idx += 256) {
        int row_id = idx / ROWW;            // 0..14  (= c*5 + kh)
        int col    = idx - row_id * ROWW;   // 0..67
        int c  = row_id / KK;
        int kh = row_id - c * KK;
        int r  = y + kh - PADC;
        int cx = col - PADC;
        float v = 0.0f;
        if ((unsigned)r < HH && (unsigned)cx < WW)
            v = x[((n * CH + c) * HH + r) * WW + cx];
        xs[idx] = v;
    }

    // ---- stage weights: ws[f*124 + (c*5+kh)*8 + kw] = W[f,c,kh,kw] ----
    for (int idx = t; idx < NF * 75; idx += 256) {
        int f = idx / 75;
        int d = idx - f * 75;
        int c   = d / 25;
        int rem = d - c * 25;
        int kh  = rem / 5;
        int kw  = rem - kh * 5;
        ws[f * WSTRIDE + (c * KK + kh) * 8 + kw] = Wt[idx];
    }
    __syncthreads();

    // ---- per-filter ||W_f||^2 (one thread per filter, once per block) ----
    if (t < NF) {
        float s = 0.0f;
        const float* wf = &ws[t * WSTRIDE];
        #pragma unroll
        for (int rr = 0; rr < NROWS; ++rr)
            #pragma unroll
            for (int kw = 0; kw < KK; ++kw) {
                float w = wf[rr * 8 + kw];
                s += w * w;
            }
        w2s[t] = s;
    }

    // ---- register tile: 4 pixels x 4 filters per thread ----
    const int p4 = t & 15;        // pixel group: x0 = p4*4
    const int f4 = t >> 4;        // filter group: fb = f4*4
    const int x0 = p4 * 4;
    const int fb = f4 * 4;

    float acc[4][4];              // [filter j][pixel i]
    #pragma unroll
    for (int j = 0; j < 4; ++j)
        #pragma unroll
        for (int i = 0; i < 4; ++i)
            acc[j][i] = 0.0f;
    float ps2[4] = {0.0f, 0.0f, 0.0f, 0.0f};

    #pragma unroll
    for (int rr = 0; rr < NROWS; ++rr) {
        // 8-float sliding window for 4 pixels (two aligned b128 reads)
        const float4 wlo = *(const float4*)&xs[rr * ROWW + x0];
        const float4 whi = *(const float4*)&xs[rr * ROWW + x0 + 4];
        float win[8] = {wlo.x, wlo.y, wlo.z, wlo.w,
                        whi.x, whi.y, whi.z, whi.w};

        #pragma unroll
        for (int i = 0; i < 4; ++i)
            #pragma unroll
            for (int kw = 0; kw < KK; ++kw)
                ps2[i] += win[i + kw] * win[i + kw];

        #pragma unroll
        for (int j = 0; j < 4; ++j) {
            const float4 w03 = *(const float4*)&ws[(fb + j) * WSTRIDE + rr * 8];
            const float  w4  = ws[(fb + j) * WSTRIDE + rr * 8 + 4];
            const float wv[5] = {w03.x, w03.y, w03.z, w03.w, w4};
            #pragma unroll
            for (int i = 0; i < 4; ++i)
                #pragma unroll
                for (int kw = 0; kw < KK; ++kw)
                    acc[j][i] += wv[kw] * win[i + kw];
        }
    }

    __syncthreads();   // w2s ready

    // ---- epilogue: out[((n*64 + f)*64 + y)*64 + x], float4 stores ----
    #pragma unroll
    for (int j = 0; j < 4; ++j) {
        const float wsq = w2s[fb + j];
        float4 o;
        o.x = acc[j][0] - 0.5f * (ps2[0] + wsq);
        o.y = acc[j][1] - 0.5f * (ps2[1] + wsq);
        o.z = acc[j][2] - 0.5f * (ps2[2] + wsq);
        o.w = acc[j][3] - 0.5f * (ps2[3] + wsq);
        *(float4*)&out[((n * NF + fb + j) * HH + y) * WW + x0] = o;
    }
}

extern "C" void kernel_launch(void* const* d_in, const int* in_sizes, int n_in,
                              void* d_out, int out_size, void* d_ws, size_t ws_size,
                              hipStream_t stream) {
    const float* x  = (const float*)d_in[0];   // 8*3*64*64
    const float* Wt = (const float*)d_in[1];   // 64*3*5*5
    float* out = (float*)d_out;                // 8*64*64*64
    (void)in_sizes; (void)n_in; (void)out_size; (void)d_ws; (void)ws_size;

    dim3 grid(8 * 64);   // one block per (n, y) output row
    dim3 block(256);
    hipLaunchKernelGGL(euclid_conv_kernel, grid, block, 0, stream, x, Wt, out);
}